// Round 14
// baseline (95.287 us; speedup 1.0000x reference)
//
#include <hip/hip_runtime.h>

#define DECAY 0.99f
#define ONE_MINUS_DECAY 0.01f
#define EPSF 1e-5f
#define BETA 0.25f

constexpr int M_ = 32768;            // rows (B*H*W)
constexpr int N_ = 1024;             // codes
constexpr int K_ = 128;              // dim

typedef _Float16 f16;
typedef f16 f16x8 __attribute__((ext_vector_type(8)));
typedef float f32x4 __attribute__((ext_vector_type(4)));

#define GLOAD_LDS(g, l) __builtin_amdgcn_global_load_lds( \
    (const __attribute__((address_space(1))) void*)(g),   \
    (__attribute__((address_space(3))) void*)(l), 16, 0, 0)

// packed top-3 insert: (score<<10)|idx, unsigned order == (score, idx) lexicographic
#define PINS(p) { unsigned _t2 = m1 > (p) ? m1 : (p); m1 = m1 < (p) ? m1 : (p); \
                  unsigned _t3 = m2 > _t2 ? m2 : _t2;  m2 = m2 < _t2 ? m2 : _t2; \
                  m3 = m3 < _t3 ? m3 : _t3; }

// ---- workspace layout (bytes) ----
constexpr size_t WS_FLAT   = 0;                                   // M*K fp32 (16MB)
constexpr size_t WS_XH     = WS_FLAT   + (size_t)M_ * K_ * 4;     // M*K f16, tile-swizzled
constexpr size_t WS_EH     = WS_XH     + (size_t)M_ * K_ * 2;     // N*K f16 (-2e)
constexpr size_t WS_NL     = WS_EH     + (size_t)N_ * K_ * 2;     // N fp32 ||e||^2
constexpr size_t WS_PPK    = WS_NL     + (size_t)N_ * 4;          // 4*M uint4 packed top-3
constexpr size_t WS_IDX    = WS_PPK    + (size_t)4 * M_ * 16;     // M int
constexpr size_t WS_COUNTS = WS_IDX    + (size_t)M_ * 4;          // N int  (zeroed in transpose)
constexpr size_t WS_CUR    = WS_COUNTS + (size_t)N_ * 4;          // N int  (zeroed in transpose)
constexpr size_t WS_DONE   = WS_CUR    + (size_t)N_ * 4;          // 16B    (zeroed in transpose)
constexpr size_t WS_ESUM   = WS_DONE   + 16;                      // N*K f32 (zeroed in bucket)
constexpr size_t WS_OFFS   = WS_ESUM   + (size_t)N_ * K_ * 4;     // N int
constexpr size_t WS_ROWS   = WS_OFFS   + (size_t)N_ * 4;          // M int
constexpr size_t WS_LPART  = WS_ROWS   + (size_t)M_ * 4;          // 512 doubles (chunksum)
constexpr size_t WS_NSUM   = WS_LPART  + (size_t)4096 * 8;        // 1 float

// ---- output layout (float elements) ----
constexpr size_t O_ZQST = 0;
constexpr size_t O_LOSS = O_ZQST + (size_t)M_ * K_;
constexpr size_t O_IDX  = O_LOSS + 1;
constexpr size_t O_ZQ   = O_IDX  + (size_t)M_;
constexpr size_t O_ZE   = O_ZQ   + (size_t)M_ * K_;
constexpr size_t O_EMB  = O_ZE   + (size_t)M_ * K_;
constexpr size_t O_NCS  = O_EMB  + (size_t)N_ * K_;
constexpr size_t O_NEA  = O_NCS  + (size_t)N_;

// (B,C,H,W) -> flat[r][c] fp32 + xh f16 tile-swizzled + z_e out.
// Fused: block j converts code j (eh, nl); blocks 0-1 zero counts+cur,
// block 2 zeroes the done counter (no memset — round-8/9 lesson).
__global__ void transpose_kernel(const float* __restrict__ ze,
                                 const float* __restrict__ embed,
                                 float* __restrict__ flat,
                                 f16* __restrict__ xh,
                                 float* __restrict__ out_ze,
                                 f16* __restrict__ eh, float* __restrict__ nl,
                                 uint4* __restrict__ zero8k) {
    __shared__ float tile[128][33];
    __shared__ float ered[2];
    const int j = blockIdx.x;                        // doubles as code id
    const int t = threadIdx.x;
    if (t < 128) {                                   // e-cvt for code j
        float a = embed[(size_t)j * K_ + t];
        eh[(size_t)j * K_ + t] = (f16)(-2.f * a);
        float s = a * a;
        #pragma unroll
        for (int off = 32; off; off >>= 1) s += __shfl_down(s, off);
        if ((t & 63) == 0) ered[t >> 6] = s;
    }
    if (j < 2) zero8k[j * 256 + t] = make_uint4(0u, 0u, 0u, 0u);
    if (j == 2 && t == 0) zero8k[512] = make_uint4(0u, 0u, 0u, 0u);  // done ctr

    int b = j >> 5, h = j & 31;
    const size_t base = (size_t)b * 131072 + (size_t)h * 32;
    #pragma unroll
    for (int i = 0; i < 4; ++i) {                    // 1024 float4 loads
        int q = i * 256 + t;
        int c = q >> 3, w4 = (q & 7) * 4;
        float4 v = *(const float4*)(ze + base + (size_t)c * 1024 + w4);
        tile[c][w4 + 0] = v.x; tile[c][w4 + 1] = v.y;
        tile[c][w4 + 2] = v.z; tile[c][w4 + 3] = v.w;
        *(float4*)(out_ze + base + (size_t)c * 1024 + w4) = v;
    }
    __syncthreads();
    if (t == 0) nl[j] = ered[0] + ered[1];
    const int r0 = b * 1024 + h * 32;
    #pragma unroll
    for (int i = 0; i < 2; ++i) {                    // 8-wide row spans
        int w = (t >> 4) + i * 16;
        int c0 = (t & 15) * 8;
        int r = r0 + w;
        float vv[8];
        #pragma unroll
        for (int q = 0; q < 8; ++q) vv[q] = tile[c0 + q][w];
        *(float4*)(flat + (size_t)r * K_ + c0)     = make_float4(vv[0], vv[1], vv[2], vv[3]);
        *(float4*)(flat + (size_t)r * K_ + c0 + 4) = make_float4(vv[4], vv[5], vv[6], vv[7]);
        f16x8 hv;
        #pragma unroll
        for (int q = 0; q < 8; ++q) hv[q] = (f16)vv[q];
        size_t xa = (size_t)r * K_ + ((((c0 >> 3) ^ (r & 15)) << 3));
        *(f16x8*)(xh + xa) = hv;
    }
}

// MFMA NN search. Grid (512, 4): one 64-row x-tile per block (round-13 used
// 4 tiles/block at 2 blocks/CU — latency-bound behind per-tile barriers; this
// gives 4 blocks/CU so folds overlap other waves' MFMA). Single-f16 x and e;
// packed fixed-point top-3 per row; exact fp32 re-rank in refine.
__global__ __launch_bounds__(256, 4)
void nn_kernel(const f16* __restrict__ xh_g,
               const f16* __restrict__ eh, const float* __restrict__ nl,
               uint4* __restrict__ p_pk) {
    __shared__ __align__(16) f16 xbh[64 * 128];      // 16KB
    __shared__ uint4 pm[4][64];                      // 4KB packed merge
    const int t = threadIdx.x;
    const int wave = t >> 6, lane = t & 63;
    const int crow = lane & 15, g = lane >> 4;
    const int c0 = blockIdx.y * 256 + wave * 64;
    const int R0 = blockIdx.x * 64;

    // stage this block's x-tile first so loads fly under e-frag setup
    {
        const size_t tb = (size_t)blockIdx.x * 8192;
        #pragma unroll
        for (int i = 0; i < 4; ++i) {
            int q = wave * 4 + i;                    // 16 x 1KB chunks
            GLOAD_LDS(xh_g + tb + q * 512 + lane * 8, &xbh[q * 512]);
        }
    }

    f16x8 efh[4][4];                                 // 64 VGPR persistent
    #pragma unroll
    for (int m = 0; m < 4; ++m)
        #pragma unroll
        for (int kt = 0; kt < 4; ++kt)
            efh[m][kt] = *(const f16x8*)(eh + (size_t)(c0 + m * 16 + crow) * K_ + kt * 32 + g * 8);
    f32x4 nlinit[4];
    #pragma unroll
    for (int m = 0; m < 4; ++m) {
        f32x4 v = *(const f32x4*)(nl + c0 + m * 16 + g * 4);
        nlinit[m] = v + 1024.f;                      // (acc)*1024 = s*1024 + 2^20
    }
    const unsigned cbase = (unsigned)(c0 + g * 4);

    __syncthreads();                                 // vmcnt drained -> xbh ready
    #pragma unroll
    for (int st = 0; st < 4; ++st) {
        f32x4 acc[4];
        #pragma unroll
        for (int m = 0; m < 4; ++m) acc[m] = nlinit[m];
        #pragma unroll
        for (int kt = 0; kt < 4; ++kt) {
            int off = (st * 16 + crow) * 128 + ((((kt << 2) + g) ^ crow) << 3);
            f16x8 bh = *(const f16x8*)&xbh[off];
            #pragma unroll
            for (int m = 0; m < 4; ++m)
                acc[m] = __builtin_amdgcn_mfma_f32_16x16x32_f16(efh[m][kt], bh, acc[m], 0, 0, 0);
        }
        unsigned m1 = ~0u, m2 = ~0u, m3 = ~0u;
        #pragma unroll
        for (int m = 0; m < 4; ++m)
            #pragma unroll
            for (int q = 0; q < 4; ++q) {
                unsigned u = (unsigned)(acc[m][q] * 1024.f);
                unsigned p = (u << 10) + cbase + (unsigned)(m * 16 + q);
                PINS(p);
            }
        #pragma unroll
        for (int d = 16; d <= 32; d <<= 1) {         // merge 4 lane-groups per row
            unsigned o1 = (unsigned)__shfl_xor((int)m1, d);
            unsigned o2 = (unsigned)__shfl_xor((int)m2, d);
            unsigned o3 = (unsigned)__shfl_xor((int)m3, d);
            PINS(o1); PINS(o2); PINS(o3);
        }
        if (lane < 16) pm[wave][st * 16 + crow] = make_uint4(m1, m2, m3, 0u);
    }
    __syncthreads();                                 // pm ready
    if (lane < 16) {                                 // each wave merges 16 rows
        int row = wave * 16 + lane;
        uint4 a = pm[0][row];
        unsigned m1 = a.x, m2 = a.y, m3 = a.z;
        #pragma unroll
        for (int w = 1; w < 4; ++w) {
            uint4 b = pm[w][row];
            PINS(b.x); PINS(b.y); PINS(b.z);
        }
        p_pk[(size_t)blockIdx.y * M_ + R0 + row] = make_uint4(m1, m2, m3, 0u);
    }
}

// merge 4 split top-3s; exact fp32 recompute of the 3 candidates ONLY when the
// quantized gap <= 0.5 (~4% of rows). Last block (done-counter) additionally
// performs the old ema_a work: ncs, nws, exclusive count scan -> offs.
__global__ void reduce_refine_kernel(const uint4* __restrict__ p_pk,
                                     const float* __restrict__ flat,
                                     const float* __restrict__ embed,
                                     const float* __restrict__ nl,
                                     const float* __restrict__ cluster_size,
                                     int* __restrict__ idxws, float* __restrict__ out_idx,
                                     int* __restrict__ counts,
                                     unsigned* __restrict__ done,
                                     float* __restrict__ out_ncs, float* __restrict__ nws,
                                     int* __restrict__ offs) {
    int r = blockIdx.x * 256 + threadIdx.x;
    uint4 a = p_pk[r];
    unsigned m1 = a.x, m2 = a.y, m3 = a.z;
    #pragma unroll
    for (int y = 1; y < 4; ++y) {
        uint4 b = p_pk[(size_t)y * M_ + r];
        PINS(b.x); PINS(b.y); PINS(b.z);
    }
    int i1 = (int)(m1 & 1023u);
    if ((m2 >> 10) - (m1 >> 10) <= 512u) {
        int i2 = (int)(m2 & 1023u), i3 = (int)(m3 & 1023u);
        const float* x  = flat  + (size_t)r * K_;
        const float* e1 = embed + (size_t)i1 * K_;
        const float* e2 = embed + (size_t)i2 * K_;
        const float* e3 = embed + (size_t)i3 * K_;
        float d1 = 0.f, d2 = 0.f, d3 = 0.f;
        for (int k = 0; k < K_; ++k) {
            float xv = x[k];
            d1 = fmaf(xv, e1[k], d1);
            d2 = fmaf(xv, e2[k], d2);
            d3 = fmaf(xv, e3[k], d3);
        }
        float s1 = fmaf(-2.f, d1, nl[i1]);
        float s2 = fmaf(-2.f, d2, nl[i2]);
        float s3 = fmaf(-2.f, d3, nl[i3]);
        float bs = s1; int bi = i1;
        if (s2 < bs || (s2 == bs && i2 < bi)) { bs = s2; bi = i2; }
        if (s3 < bs || (s3 == bs && i3 < bi)) { bs = s3; bi = i3; }
        i1 = bi;
    }
    idxws[r] = i1;
    out_idx[r] = (float)i1;
    atomicAdd(counts + i1, 1);

    // ---- last-block tail: ncs + nws + count scan (replaces ema_a kernel) ----
    __shared__ unsigned isLast;
    __threadfence();
    if (threadIdx.x == 0) isLast = (atomicAdd(done, 1u) == gridDim.x - 1) ? 1u : 0u;
    __syncthreads();
    if (isLast) {
        const int t = threadIdx.x;                   // 4 codes/thread
        __shared__ int sc[256];
        __shared__ float sf[256];
        int c4[4], pre[4];
        float nsum = 0.f;
        #pragma unroll
        for (int i = 0; i < 4; ++i) {
            int j = t * 4 + i;
            c4[i] = atomicAdd(counts + j, 0);        // coherent-point read
            float ncs = cluster_size[j] * DECAY + ONE_MINUS_DECAY * (float)c4[i];
            out_ncs[j] = ncs;
            nsum += ncs;
        }
        pre[0] = 0; pre[1] = c4[0]; pre[2] = pre[1] + c4[1]; pre[3] = pre[2] + c4[2];
        int csum = pre[3] + c4[3];
        sc[t] = csum;
        sf[t] = nsum;
        __syncthreads();
        for (int d = 1; d < 256; d <<= 1) {          // Hillis-Steele inclusive
            int v = (t >= d) ? sc[t - d] : 0;
            float f = (t >= d) ? sf[t - d] : 0.f;
            __syncthreads();
            sc[t] += v; sf[t] += f;
            __syncthreads();
        }
        int base = sc[t] - csum;
        #pragma unroll
        for (int i = 0; i < 4; ++i) offs[t * 4 + i] = base + pre[i];
        if (t == 255) nws[0] = sf[255];
    }
}

// pure gather: z_q_st == z_q to 1 ulp (z_e + (z_q - z_e)); no z_e read, no loss.
__global__ void gather_kernel(const float* __restrict__ embed,
                              const int* __restrict__ idxws,
                              float* __restrict__ out_st, float* __restrict__ out_zq) {
    int q = blockIdx.x * 256 + threadIdx.x;
    int o0 = q * 4;
    int rbase = (o0 >> 17) * 1024 + (o0 & 1023);
    int c = (o0 >> 10) & 127;
    int4 jj = *(const int4*)(idxws + rbase);         // r..r+3 contiguous
    float4 zq = make_float4(embed[(size_t)jj.x * K_ + c], embed[(size_t)jj.y * K_ + c],
                            embed[(size_t)jj.z * K_ + c], embed[(size_t)jj.w * K_ + c]);
    *(float4*)(out_st + o0) = zq;
    *(float4*)(out_zq + o0) = zq;
}

// scatter row ids into per-code buckets; LDS-histogram pre-aggregation keeps
// global atomic depth per code <= #blocks regardless of cluster skew.
// Also zeroes esum (512KB) for chunksum (kernel-boundary ordering).
__global__ void bucket_kernel(const int* __restrict__ idxws, const int* __restrict__ offs,
                              int* __restrict__ cur, int* __restrict__ rows,
                              float4* __restrict__ esum_z) {
    __shared__ int lcnt[N_];
    __shared__ int lbase[N_];
    int t = threadIdx.x;                       // 256
    esum_z[blockIdx.x * 256 + t] = make_float4(0.f, 0.f, 0.f, 0.f);
    #pragma unroll
    for (int i = 0; i < 4; ++i) lcnt[i * 256 + t] = 0;
    __syncthreads();
    int r = blockIdx.x * 256 + t;
    int j = idxws[r];
    atomicAdd(&lcnt[j], 1);                    // LDS atomic
    __syncthreads();
    #pragma unroll
    for (int i = 0; i < 4; ++i) {
        int c = i * 256 + t;
        int n = lcnt[c];
        lbase[c] = n ? atomicAdd(cur + c, n) : 0;
        lcnt[c] = 0;
    }
    __syncthreads();
    int p = atomicAdd(&lcnt[j], 1) + lbase[j];
    rows[offs[j] + p] = r;
}

// load-balanced segmented sum + loss: 64 sorted rows per block; one esum atomic
// per code-segment boundary; loss = sum (x - e_code)^2 accumulated per-thread
// (coalesced e reads, L2-hot) -> one double partial per block.
__global__ void chunksum_kernel(const float* __restrict__ flat,
                                const float* __restrict__ embed,
                                const int* __restrict__ rows,
                                const int* __restrict__ idxws,
                                float* __restrict__ esum,
                                double* __restrict__ lpart) {
    __shared__ int srid[64];
    __shared__ int scd[65];
    __shared__ double lred[128];
    int k = threadIdx.x;                       // 128 threads = K dim
    int b = blockIdx.x;                        // 512 chunks
    if (k < 64) {
        int r = rows[b * 64 + k];
        srid[k] = r;
        scd[k] = idxws[r];
    }
    if (k == 64) scd[64] = -1;                 // sentinel != any code
    __syncthreads();
    float acc = 0.f;
    double lacc = 0.0;
    #pragma unroll 1
    for (int i0 = 0; i0 < 64; i0 += 8) {
        float v[8], ev[8];
        #pragma unroll
        for (int i = 0; i < 8; ++i)
            v[i] = flat[(size_t)srid[i0 + i] * K_ + k];          // 8 independent loads
        #pragma unroll
        for (int i = 0; i < 8; ++i)
            ev[i] = embed[(size_t)scd[i0 + i] * K_ + k];         // coalesced, L2-hot
        #pragma unroll
        for (int i = 0; i < 8; ++i) {
            acc += v[i];
            float diff = ev[i] - v[i];
            lacc = fmaf((double)diff, (double)diff, lacc);
            int p = i0 + i;
            if (scd[p + 1] != scd[p]) {        // wave-uniform branch
                atomicAdd(esum + (size_t)scd[p] * K_ + k, acc);
                acc = 0.f;
            }
        }
    }
    lred[k] = lacc;
    __syncthreads();
    for (int s = 64; s; s >>= 1) {
        if (k < s) lred[k] += lred[k + s];
        __syncthreads();
    }
    if (k == 0) lpart[b] = lred[0];
}

// EMA + normalize epilogue on esum; block 0 also finalizes the loss from
// chunksum's 512 partials (runs after chunksum -> no cross-call state).
__global__ void ema_b_kernel(const float* __restrict__ embed_avg,
                             const float* __restrict__ esum,
                             const float* __restrict__ out_ncs,
                             const float* __restrict__ nws,
                             const double* __restrict__ lpart,
                             float* __restrict__ out_nea, float* __restrict__ out_emb,
                             float* __restrict__ out_loss) {
    int o = blockIdx.x * 256 + threadIdx.x;
    int j = o >> 7;
    float navg = embed_avg[o] * DECAY + ONE_MINUS_DECAY * esum[o];
    out_nea[o] = navg;
    float n = nws[0];
    float denom = n + 1024.0f * EPSF;
    float cs = (out_ncs[j] + EPSF) / denom * n;
    float cs_safe = fmaxf(cs, EPSF);
    float v = navg / cs_safe;
    if (v != v) v = 0.f;
    v = fminf(fmaxf(v, -2.f), 2.f);
    out_emb[o] = v;
    if (blockIdx.x == 0) {
        __shared__ double red[256];
        int t = threadIdx.x;
        red[t] = lpart[t] + lpart[t + 256];
        __syncthreads();
        for (int s = 128; s; s >>= 1) {
            if (t < s) red[t] += red[t + s];
            __syncthreads();
        }
        if (t == 0) out_loss[0] = (float)((double)BETA * (red[0] / 4194304.0));
    }
}

extern "C" void kernel_launch(void* const* d_in, const int* in_sizes, int n_in,
                              void* d_out, int out_size, void* d_ws, size_t ws_size,
                              hipStream_t stream) {
    const float* z_e          = (const float*)d_in[0];
    const float* embed        = (const float*)d_in[1];
    const float* cluster_size = (const float*)d_in[2];
    const float* embed_avg    = (const float*)d_in[3];
    float* out = (float*)d_out;
    char*  ws  = (char*)d_ws;

    float*    flat   = (float*)(ws + WS_FLAT);
    f16*      xhp    = (f16*)  (ws + WS_XH);
    f16*      ehp    = (f16*)  (ws + WS_EH);
    float*    nlp    = (float*)(ws + WS_NL);
    uint4*    p_pk   = (uint4*)(ws + WS_PPK);
    int*      idxws  = (int*)  (ws + WS_IDX);
    int*      counts = (int*)  (ws + WS_COUNTS);
    int*      cur    = (int*)  (ws + WS_CUR);
    unsigned* done   = (unsigned*)(ws + WS_DONE);
    float*    esum   = (float*)(ws + WS_ESUM);
    int*      offs   = (int*)  (ws + WS_OFFS);
    int*      rows   = (int*)  (ws + WS_ROWS);
    double*   lpart  = (double*)(ws + WS_LPART);
    float*    nws    = (float*)(ws + WS_NSUM);

    transpose_kernel<<<1024, 256, 0, stream>>>(z_e, embed, flat, xhp, out + O_ZE,
                                               ehp, nlp, (uint4*)(ws + WS_COUNTS));
    nn_kernel<<<dim3(512, 4), 256, 0, stream>>>(xhp, ehp, nlp, p_pk);
    reduce_refine_kernel<<<M_ / 256, 256, 0, stream>>>(p_pk, flat, embed, nlp,
                                                       cluster_size, idxws, out + O_IDX,
                                                       counts, done, out + O_NCS, nws, offs);
    gather_kernel<<<4096, 256, 0, stream>>>(embed, idxws, out + O_ZQST, out + O_ZQ);
    bucket_kernel<<<M_ / 256, 256, 0, stream>>>(idxws, offs, cur, rows,
                                                (float4*)(ws + WS_ESUM));
    chunksum_kernel<<<M_ / 64, K_, 0, stream>>>(flat, embed, rows, idxws, esum, lpart);
    ema_b_kernel<<<(N_ * K_) / 256, 256, 0, stream>>>(embed_avg, esum, out + O_NCS, nws,
                                                      lpart, out + O_NEA, out + O_EMB,
                                                      out + O_LOSS);
}

// Round 15
// 94.107 us; speedup vs baseline: 1.0125x; 1.0125x over previous
//
#include <hip/hip_runtime.h>

#define DECAY 0.99f
#define ONE_MINUS_DECAY 0.01f
#define EPSF 1e-5f
#define BETA 0.25f

constexpr int M_ = 32768;            // rows (B*H*W)
constexpr int N_ = 1024;             // codes
constexpr int K_ = 128;              // dim

typedef _Float16 f16;
typedef f16 f16x8 __attribute__((ext_vector_type(8)));
typedef float f32x4 __attribute__((ext_vector_type(4)));

#define GLOAD_LDS(g, l) __builtin_amdgcn_global_load_lds( \
    (const __attribute__((address_space(1))) void*)(g),   \
    (__attribute__((address_space(3))) void*)(l), 16, 0, 0)

// packed top-3 insert: (score<<10)|idx, unsigned order == (score, idx) lexicographic
#define PINS(p) { unsigned _t2 = m1 > (p) ? m1 : (p); m1 = m1 < (p) ? m1 : (p); \
                  unsigned _t3 = m2 > _t2 ? m2 : _t2;  m2 = m2 < _t2 ? m2 : _t2; \
                  m3 = m3 < _t3 ? m3 : _t3; }

// ---- workspace layout (bytes) ----
constexpr size_t WS_FLAT   = 0;                                   // M*K fp32 (16MB)
constexpr size_t WS_XH     = WS_FLAT   + (size_t)M_ * K_ * 4;     // M*K f16, tile-swizzled
constexpr size_t WS_EH     = WS_XH     + (size_t)M_ * K_ * 2;     // N*K f16 (-2e)
constexpr size_t WS_NL     = WS_EH     + (size_t)N_ * K_ * 2;     // N fp32 ||e||^2
constexpr size_t WS_PPK    = WS_NL     + (size_t)N_ * 4;          // 4*M uint4 packed top-3
constexpr size_t WS_IDX    = WS_PPK    + (size_t)4 * M_ * 16;     // M int
constexpr size_t WS_COUNTS = WS_IDX    + (size_t)M_ * 4;          // N int  (zeroed in transpose)
constexpr size_t WS_CUR    = WS_COUNTS + (size_t)N_ * 4;          // N int  (zeroed in transpose)
constexpr size_t WS_DONE   = WS_CUR    + (size_t)N_ * 4;          // 16B    (zeroed in transpose)
constexpr size_t WS_ESUM   = WS_DONE   + 16;                      // N*K f32 (zeroed in bucket)
constexpr size_t WS_OFFS   = WS_ESUM   + (size_t)N_ * K_ * 4;     // N int
constexpr size_t WS_ROWS   = WS_OFFS   + (size_t)N_ * 4;          // M int
constexpr size_t WS_LPART  = WS_ROWS   + (size_t)M_ * 4;          // 512 doubles (chunksum)
constexpr size_t WS_NSUM   = WS_LPART  + (size_t)4096 * 8;        // 1 float

// ---- output layout (float elements) ----
constexpr size_t O_ZQST = 0;
constexpr size_t O_LOSS = O_ZQST + (size_t)M_ * K_;
constexpr size_t O_IDX  = O_LOSS + 1;
constexpr size_t O_ZQ   = O_IDX  + (size_t)M_;
constexpr size_t O_ZE   = O_ZQ   + (size_t)M_ * K_;
constexpr size_t O_EMB  = O_ZE   + (size_t)M_ * K_;
constexpr size_t O_NCS  = O_EMB  + (size_t)N_ * K_;
constexpr size_t O_NEA  = O_NCS  + (size_t)N_;

// (B,C,H,W) -> flat[r][c] fp32 + xh f16 tile-swizzled + z_e out.
// Fused: block j converts code j (eh, nl); blocks 0-1 zero counts+cur,
// block 2 zeroes the done counter (no memset — round-8/9 lesson).
__global__ void transpose_kernel(const float* __restrict__ ze,
                                 const float* __restrict__ embed,
                                 float* __restrict__ flat,
                                 f16* __restrict__ xh,
                                 float* __restrict__ out_ze,
                                 f16* __restrict__ eh, float* __restrict__ nl,
                                 uint4* __restrict__ zero8k) {
    __shared__ float tile[128][33];
    __shared__ float ered[2];
    const int j = blockIdx.x;                        // doubles as code id
    const int t = threadIdx.x;
    if (t < 128) {                                   // e-cvt for code j
        float a = embed[(size_t)j * K_ + t];
        eh[(size_t)j * K_ + t] = (f16)(-2.f * a);
        float s = a * a;
        #pragma unroll
        for (int off = 32; off; off >>= 1) s += __shfl_down(s, off);
        if ((t & 63) == 0) ered[t >> 6] = s;
    }
    if (j < 2) zero8k[j * 256 + t] = make_uint4(0u, 0u, 0u, 0u);
    if (j == 2 && t == 0) zero8k[512] = make_uint4(0u, 0u, 0u, 0u);  // done ctr

    int b = j >> 5, h = j & 31;
    const size_t base = (size_t)b * 131072 + (size_t)h * 32;
    #pragma unroll
    for (int i = 0; i < 4; ++i) {                    // 1024 float4 loads
        int q = i * 256 + t;
        int c = q >> 3, w4 = (q & 7) * 4;
        float4 v = *(const float4*)(ze + base + (size_t)c * 1024 + w4);
        tile[c][w4 + 0] = v.x; tile[c][w4 + 1] = v.y;
        tile[c][w4 + 2] = v.z; tile[c][w4 + 3] = v.w;
        *(float4*)(out_ze + base + (size_t)c * 1024 + w4) = v;
    }
    __syncthreads();
    if (t == 0) nl[j] = ered[0] + ered[1];
    const int r0 = b * 1024 + h * 32;
    #pragma unroll
    for (int i = 0; i < 2; ++i) {                    // 8-wide row spans
        int w = (t >> 4) + i * 16;
        int c0 = (t & 15) * 8;
        int r = r0 + w;
        float vv[8];
        #pragma unroll
        for (int q = 0; q < 8; ++q) vv[q] = tile[c0 + q][w];
        *(float4*)(flat + (size_t)r * K_ + c0)     = make_float4(vv[0], vv[1], vv[2], vv[3]);
        *(float4*)(flat + (size_t)r * K_ + c0 + 4) = make_float4(vv[4], vv[5], vv[6], vv[7]);
        f16x8 hv;
        #pragma unroll
        for (int q = 0; q < 8; ++q) hv[q] = (f16)vv[q];
        size_t xa = (size_t)r * K_ + ((((c0 >> 3) ^ (r & 15)) << 3));
        *(f16x8*)(xh + xa) = hv;
    }
}

// MFMA NN search — round-13 shape (grid (128,4), 4 x-tiles per block): e-frag
// setup amortized over 4 tiles. Round-14's one-tile-per-block variant paid the
// 64KB/block e-frag reload 4x as often and regressed (+3.4us). Single-f16 x/e;
// packed fixed-point top-3 per row; exact fp32 re-rank in refine.
__global__ __launch_bounds__(256, 4)
void nn_kernel(const f16* __restrict__ xh_g,
               const f16* __restrict__ eh, const float* __restrict__ nl,
               uint4* __restrict__ p_pk) {
    __shared__ __align__(16) f16 xbh[64 * 128];      // 16KB
    __shared__ uint4 pm[4][64];                      // 4KB packed merge
    const int t = threadIdx.x;
    const int wave = t >> 6, lane = t & 63;
    const int crow = lane & 15, g = lane >> 4;
    const int c0 = blockIdx.y * 256 + wave * 64;

    f16x8 efh[4][4];                                 // 64 VGPR persistent
    #pragma unroll
    for (int m = 0; m < 4; ++m)
        #pragma unroll
        for (int kt = 0; kt < 4; ++kt)
            efh[m][kt] = *(const f16x8*)(eh + (size_t)(c0 + m * 16 + crow) * K_ + kt * 32 + g * 8);
    f32x4 nlinit[4];
    #pragma unroll
    for (int m = 0; m < 4; ++m) {
        f32x4 v = *(const f32x4*)(nl + c0 + m * 16 + g * 4);
        nlinit[m] = v + 1024.f;                      // (acc)*1024 = s*1024 + 2^20
    }
    const unsigned cbase = (unsigned)(c0 + g * 4);

    auto stage = [&](int bt) {
        const size_t tb = (size_t)(blockIdx.x * 4 + bt) * 8192;
        #pragma unroll
        for (int i = 0; i < 4; ++i) {
            int q = wave * 4 + i;                    // 16 x 1KB chunks
            GLOAD_LDS(xh_g + tb + q * 512 + lane * 8, &xbh[q * 512]);
        }
    };

    stage(0);
    __syncthreads();                                 // vmcnt drained -> xb ready
    for (int bt = 0; bt < 4; ++bt) {
        const int R0 = (blockIdx.x * 4 + bt) * 64;
        #pragma unroll
        for (int st = 0; st < 4; ++st) {
            f32x4 acc[4];
            #pragma unroll
            for (int m = 0; m < 4; ++m) acc[m] = nlinit[m];
            #pragma unroll
            for (int kt = 0; kt < 4; ++kt) {
                int off = (st * 16 + crow) * 128 + ((((kt << 2) + g) ^ crow) << 3);
                f16x8 bh = *(const f16x8*)&xbh[off];
                #pragma unroll
                for (int m = 0; m < 4; ++m)
                    acc[m] = __builtin_amdgcn_mfma_f32_16x16x32_f16(efh[m][kt], bh, acc[m], 0, 0, 0);
            }
            unsigned m1 = ~0u, m2 = ~0u, m3 = ~0u;
            #pragma unroll
            for (int m = 0; m < 4; ++m)
                #pragma unroll
                for (int q = 0; q < 4; ++q) {
                    unsigned u = (unsigned)(acc[m][q] * 1024.f);
                    unsigned p = (u << 10) + cbase + (unsigned)(m * 16 + q);
                    PINS(p);
                }
            #pragma unroll
            for (int d = 16; d <= 32; d <<= 1) {     // merge 4 lane-groups per row
                unsigned o1 = (unsigned)__shfl_xor((int)m1, d);
                unsigned o2 = (unsigned)__shfl_xor((int)m2, d);
                unsigned o3 = (unsigned)__shfl_xor((int)m3, d);
                PINS(o1); PINS(o2); PINS(o3);
            }
            if (lane < 16) pm[wave][st * 16 + crow] = make_uint4(m1, m2, m3, 0u);
        }
        __syncthreads();                             // xb consumed + pm ready
        if (bt < 3) stage(bt + 1);                   // async loads fly under merge
        if (lane < 16) {                             // each wave merges 16 rows
            int row = wave * 16 + lane;
            uint4 a = pm[0][row];
            unsigned m1 = a.x, m2 = a.y, m3 = a.z;
            #pragma unroll
            for (int w = 1; w < 4; ++w) {
                uint4 b = pm[w][row];
                PINS(b.x); PINS(b.y); PINS(b.z);
            }
            p_pk[(size_t)blockIdx.y * M_ + R0 + row] = make_uint4(m1, m2, m3, 0u);
        }
        __syncthreads();                             // vmcnt drain; pm reusable
    }
}

// merge 4 split top-3s; exact fp32 recompute of the 3 candidates ONLY when the
// quantized gap <= 0.5 (~4% of rows). Last block (done-counter) additionally
// performs the old ema_a work: ncs, nws, exclusive count scan -> offs.
__global__ void reduce_refine_kernel(const uint4* __restrict__ p_pk,
                                     const float* __restrict__ flat,
                                     const float* __restrict__ embed,
                                     const float* __restrict__ nl,
                                     const float* __restrict__ cluster_size,
                                     int* __restrict__ idxws, float* __restrict__ out_idx,
                                     int* __restrict__ counts,
                                     unsigned* __restrict__ done,
                                     float* __restrict__ out_ncs, float* __restrict__ nws,
                                     int* __restrict__ offs) {
    int r = blockIdx.x * 256 + threadIdx.x;
    uint4 a = p_pk[r];
    unsigned m1 = a.x, m2 = a.y, m3 = a.z;
    #pragma unroll
    for (int y = 1; y < 4; ++y) {
        uint4 b = p_pk[(size_t)y * M_ + r];
        PINS(b.x); PINS(b.y); PINS(b.z);
    }
    int i1 = (int)(m1 & 1023u);
    if ((m2 >> 10) - (m1 >> 10) <= 512u) {
        int i2 = (int)(m2 & 1023u), i3 = (int)(m3 & 1023u);
        const float* x  = flat  + (size_t)r * K_;
        const float* e1 = embed + (size_t)i1 * K_;
        const float* e2 = embed + (size_t)i2 * K_;
        const float* e3 = embed + (size_t)i3 * K_;
        float d1 = 0.f, d2 = 0.f, d3 = 0.f;
        for (int k = 0; k < K_; ++k) {
            float xv = x[k];
            d1 = fmaf(xv, e1[k], d1);
            d2 = fmaf(xv, e2[k], d2);
            d3 = fmaf(xv, e3[k], d3);
        }
        float s1 = fmaf(-2.f, d1, nl[i1]);
        float s2 = fmaf(-2.f, d2, nl[i2]);
        float s3 = fmaf(-2.f, d3, nl[i3]);
        float bs = s1; int bi = i1;
        if (s2 < bs || (s2 == bs && i2 < bi)) { bs = s2; bi = i2; }
        if (s3 < bs || (s3 == bs && i3 < bi)) { bs = s3; bi = i3; }
        i1 = bi;
    }
    idxws[r] = i1;
    out_idx[r] = (float)i1;
    atomicAdd(counts + i1, 1);

    // ---- last-block tail: ncs + nws + count scan (replaces ema_a kernel) ----
    __shared__ unsigned isLast;
    __threadfence();
    if (threadIdx.x == 0) isLast = (atomicAdd(done, 1u) == gridDim.x - 1) ? 1u : 0u;
    __syncthreads();
    if (isLast) {
        const int t = threadIdx.x;                   // 4 codes/thread
        __shared__ int sc[256];
        __shared__ float sf[256];
        int c4[4], pre[4];
        float nsum = 0.f;
        #pragma unroll
        for (int i = 0; i < 4; ++i) {
            int j = t * 4 + i;
            c4[i] = atomicAdd(counts + j, 0);        // coherent-point read
            float ncs = cluster_size[j] * DECAY + ONE_MINUS_DECAY * (float)c4[i];
            out_ncs[j] = ncs;
            nsum += ncs;
        }
        pre[0] = 0; pre[1] = c4[0]; pre[2] = pre[1] + c4[1]; pre[3] = pre[2] + c4[2];
        int csum = pre[3] + c4[3];
        sc[t] = csum;
        sf[t] = nsum;
        __syncthreads();
        for (int d = 1; d < 256; d <<= 1) {          // Hillis-Steele inclusive
            int v = (t >= d) ? sc[t - d] : 0;
            float f = (t >= d) ? sf[t - d] : 0.f;
            __syncthreads();
            sc[t] += v; sf[t] += f;
            __syncthreads();
        }
        int base = sc[t] - csum;
        #pragma unroll
        for (int i = 0; i < 4; ++i) offs[t * 4 + i] = base + pre[i];
        if (t == 255) nws[0] = sf[255];
    }
}

// pure gather: z_q_st == z_q to 1 ulp (z_e + (z_q - z_e)); no z_e read, no loss.
__global__ void gather_kernel(const float* __restrict__ embed,
                              const int* __restrict__ idxws,
                              float* __restrict__ out_st, float* __restrict__ out_zq) {
    int q = blockIdx.x * 256 + threadIdx.x;
    int o0 = q * 4;
    int rbase = (o0 >> 17) * 1024 + (o0 & 1023);
    int c = (o0 >> 10) & 127;
    int4 jj = *(const int4*)(idxws + rbase);         // r..r+3 contiguous
    float4 zq = make_float4(embed[(size_t)jj.x * K_ + c], embed[(size_t)jj.y * K_ + c],
                            embed[(size_t)jj.z * K_ + c], embed[(size_t)jj.w * K_ + c]);
    *(float4*)(out_st + o0) = zq;
    *(float4*)(out_zq + o0) = zq;
}

// scatter row ids into per-code buckets; LDS-histogram pre-aggregation keeps
// global atomic depth per code <= #blocks regardless of cluster skew.
// Also zeroes esum (512KB) for chunksum (kernel-boundary ordering).
__global__ void bucket_kernel(const int* __restrict__ idxws, const int* __restrict__ offs,
                              int* __restrict__ cur, int* __restrict__ rows,
                              float4* __restrict__ esum_z) {
    __shared__ int lcnt[N_];
    __shared__ int lbase[N_];
    int t = threadIdx.x;                       // 256
    esum_z[blockIdx.x * 256 + t] = make_float4(0.f, 0.f, 0.f, 0.f);
    #pragma unroll
    for (int i = 0; i < 4; ++i) lcnt[i * 256 + t] = 0;
    __syncthreads();
    int r = blockIdx.x * 256 + t;
    int j = idxws[r];
    atomicAdd(&lcnt[j], 1);                    // LDS atomic
    __syncthreads();
    #pragma unroll
    for (int i = 0; i < 4; ++i) {
        int c = i * 256 + t;
        int n = lcnt[c];
        lbase[c] = n ? atomicAdd(cur + c, n) : 0;
        lcnt[c] = 0;
    }
    __syncthreads();
    int p = atomicAdd(&lcnt[j], 1) + lbase[j];
    rows[offs[j] + p] = r;
}

// load-balanced segmented sum + loss: 64 sorted rows per block; one esum atomic
// per code-segment boundary; loss = sum (x - e_code)^2 accumulated per-thread
// (coalesced e reads, L2-hot) -> one double partial per block.
__global__ void chunksum_kernel(const float* __restrict__ flat,
                                const float* __restrict__ embed,
                                const int* __restrict__ rows,
                                const int* __restrict__ idxws,
                                float* __restrict__ esum,
                                double* __restrict__ lpart) {
    __shared__ int srid[64];
    __shared__ int scd[65];
    __shared__ double lred[128];
    int k = threadIdx.x;                       // 128 threads = K dim
    int b = blockIdx.x;                        // 512 chunks
    if (k < 64) {
        int r = rows[b * 64 + k];
        srid[k] = r;
        scd[k] = idxws[r];
    }
    if (k == 64) scd[64] = -1;                 // sentinel != any code
    __syncthreads();
    float acc = 0.f;
    double lacc = 0.0;
    #pragma unroll 1
    for (int i0 = 0; i0 < 64; i0 += 8) {
        float v[8], ev[8];
        #pragma unroll
        for (int i = 0; i < 8; ++i)
            v[i] = flat[(size_t)srid[i0 + i] * K_ + k];          // 8 independent loads
        #pragma unroll
        for (int i = 0; i < 8; ++i)
            ev[i] = embed[(size_t)scd[i0 + i] * K_ + k];         // coalesced, L2-hot
        #pragma unroll
        for (int i = 0; i < 8; ++i) {
            acc += v[i];
            float diff = ev[i] - v[i];
            lacc = fmaf((double)diff, (double)diff, lacc);
            int p = i0 + i;
            if (scd[p + 1] != scd[p]) {        // wave-uniform branch
                atomicAdd(esum + (size_t)scd[p] * K_ + k, acc);
                acc = 0.f;
            }
        }
    }
    lred[k] = lacc;
    __syncthreads();
    for (int s = 64; s; s >>= 1) {
        if (k < s) lred[k] += lred[k + s];
        __syncthreads();
    }
    if (k == 0) lpart[b] = lred[0];
}

// EMA + normalize epilogue on esum; block 0 also finalizes the loss from
// chunksum's 512 partials (runs after chunksum -> no cross-call state).
__global__ void ema_b_kernel(const float* __restrict__ embed_avg,
                             const float* __restrict__ esum,
                             const float* __restrict__ out_ncs,
                             const float* __restrict__ nws,
                             const double* __restrict__ lpart,
                             float* __restrict__ out_nea, float* __restrict__ out_emb,
                             float* __restrict__ out_loss) {
    int o = blockIdx.x * 256 + threadIdx.x;
    int j = o >> 7;
    float navg = embed_avg[o] * DECAY + ONE_MINUS_DECAY * esum[o];
    out_nea[o] = navg;
    float n = nws[0];
    float denom = n + 1024.0f * EPSF;
    float cs = (out_ncs[j] + EPSF) / denom * n;
    float cs_safe = fmaxf(cs, EPSF);
    float v = navg / cs_safe;
    if (v != v) v = 0.f;
    v = fminf(fmaxf(v, -2.f), 2.f);
    out_emb[o] = v;
    if (blockIdx.x == 0) {
        __shared__ double red[256];
        int t = threadIdx.x;
        red[t] = lpart[t] + lpart[t + 256];
        __syncthreads();
        for (int s = 128; s; s >>= 1) {
            if (t < s) red[t] += red[t + s];
            __syncthreads();
        }
        if (t == 0) out_loss[0] = (float)((double)BETA * (red[0] / 4194304.0));
    }
}

extern "C" void kernel_launch(void* const* d_in, const int* in_sizes, int n_in,
                              void* d_out, int out_size, void* d_ws, size_t ws_size,
                              hipStream_t stream) {
    const float* z_e          = (const float*)d_in[0];
    const float* embed        = (const float*)d_in[1];
    const float* cluster_size = (const float*)d_in[2];
    const float* embed_avg    = (const float*)d_in[3];
    float* out = (float*)d_out;
    char*  ws  = (char*)d_ws;

    float*    flat   = (float*)(ws + WS_FLAT);
    f16*      xhp    = (f16*)  (ws + WS_XH);
    f16*      ehp    = (f16*)  (ws + WS_EH);
    float*    nlp    = (float*)(ws + WS_NL);
    uint4*    p_pk   = (uint4*)(ws + WS_PPK);
    int*      idxws  = (int*)  (ws + WS_IDX);
    int*      counts = (int*)  (ws + WS_COUNTS);
    int*      cur    = (int*)  (ws + WS_CUR);
    unsigned* done   = (unsigned*)(ws + WS_DONE);
    float*    esum   = (float*)(ws + WS_ESUM);
    int*      offs   = (int*)  (ws + WS_OFFS);
    int*      rows   = (int*)  (ws + WS_ROWS);
    double*   lpart  = (double*)(ws + WS_LPART);
    float*    nws    = (float*)(ws + WS_NSUM);

    transpose_kernel<<<1024, 256, 0, stream>>>(z_e, embed, flat, xhp, out + O_ZE,
                                               ehp, nlp, (uint4*)(ws + WS_COUNTS));
    nn_kernel<<<dim3(128, 4), 256, 0, stream>>>(xhp, ehp, nlp, p_pk);
    reduce_refine_kernel<<<M_ / 256, 256, 0, stream>>>(p_pk, flat, embed, nlp,
                                                       cluster_size, idxws, out + O_IDX,
                                                       counts, done, out + O_NCS, nws, offs);
    gather_kernel<<<4096, 256, 0, stream>>>(embed, idxws, out + O_ZQST, out + O_ZQ);
    bucket_kernel<<<M_ / 256, 256, 0, stream>>>(idxws, offs, cur, rows,
                                                (float4*)(ws + WS_ESUM));
    chunksum_kernel<<<M_ / 64, K_, 0, stream>>>(flat, embed, rows, idxws, esum, lpart);
    ema_b_kernel<<<(N_ * K_) / 256, 256, 0, stream>>>(embed_avg, esum, out + O_NCS, nws,
                                                      lpart, out + O_NEA, out + O_EMB,
                                                      out + O_LOSS);
}

// Round 16
// 93.742 us; speedup vs baseline: 1.0165x; 1.0039x over previous
//
#include <hip/hip_runtime.h>

#define DECAY 0.99f
#define ONE_MINUS_DECAY 0.01f
#define EPSF 1e-5f
#define BETA 0.25f

constexpr int M_ = 32768;            // rows (B*H*W)
constexpr int N_ = 1024;             // codes
constexpr int K_ = 128;              // dim

typedef _Float16 f16;
typedef f16 f16x8 __attribute__((ext_vector_type(8)));
typedef float f32x4 __attribute__((ext_vector_type(4)));

#define GLOAD_LDS(g, l) __builtin_amdgcn_global_load_lds( \
    (const __attribute__((address_space(1))) void*)(g),   \
    (__attribute__((address_space(3))) void*)(l), 16, 0, 0)

// packed top-3 insert: (score<<10)|idx, unsigned order == (score, idx) lexicographic
#define PINS(p) { unsigned _t2 = m1 > (p) ? m1 : (p); m1 = m1 < (p) ? m1 : (p); \
                  unsigned _t3 = m2 > _t2 ? m2 : _t2;  m2 = m2 < _t2 ? m2 : _t2; \
                  m3 = m3 < _t3 ? m3 : _t3; }

// ---- workspace layout (bytes) ----
constexpr size_t WS_FLAT   = 0;                                   // M*K fp32 (16MB)
constexpr size_t WS_XH     = WS_FLAT   + (size_t)M_ * K_ * 4;     // M*K f16, tile-swizzled
constexpr size_t WS_EH     = WS_XH     + (size_t)M_ * K_ * 2;     // N*K f16 (-2e)
constexpr size_t WS_NL     = WS_EH     + (size_t)N_ * K_ * 2;     // N fp32 ||e||^2
constexpr size_t WS_PPK    = WS_NL     + (size_t)N_ * 4;          // 4*M uint4 packed top-3
constexpr size_t WS_IDX    = WS_PPK    + (size_t)4 * M_ * 16;     // M int
constexpr size_t WS_COUNTS = WS_IDX    + (size_t)M_ * 4;          // N int  (zeroed in transpose)
constexpr size_t WS_CUR    = WS_COUNTS + (size_t)N_ * 4;          // N int  (zeroed in transpose)
constexpr size_t WS_ESUM   = WS_CUR    + (size_t)N_ * 4;          // N*K f32 (zeroed in bucket)
constexpr size_t WS_OFFS   = WS_ESUM   + (size_t)N_ * K_ * 4;     // N int
constexpr size_t WS_ROWS   = WS_OFFS   + (size_t)N_ * 4;          // M int
constexpr size_t WS_LPART  = WS_ROWS   + (size_t)M_ * 4;          // 512 doubles (chunksum)
constexpr size_t WS_NSUM   = WS_LPART  + (size_t)4096 * 8;        // 1 float

// ---- output layout (float elements) ----
constexpr size_t O_ZQST = 0;
constexpr size_t O_LOSS = O_ZQST + (size_t)M_ * K_;
constexpr size_t O_IDX  = O_LOSS + 1;
constexpr size_t O_ZQ   = O_IDX  + (size_t)M_;
constexpr size_t O_ZE   = O_ZQ   + (size_t)M_ * K_;
constexpr size_t O_EMB  = O_ZE   + (size_t)M_ * K_;
constexpr size_t O_NCS  = O_EMB  + (size_t)N_ * K_;
constexpr size_t O_NEA  = O_NCS  + (size_t)N_;

// (B,C,H,W) -> flat[r][c] fp32 + xh f16 tile-swizzled + z_e out.
// Fused: block j converts code j (eh, nl); blocks 0-1 zero counts+cur.
__global__ void transpose_kernel(const float* __restrict__ ze,
                                 const float* __restrict__ embed,
                                 float* __restrict__ flat,
                                 f16* __restrict__ xh,
                                 float* __restrict__ out_ze,
                                 f16* __restrict__ eh, float* __restrict__ nl,
                                 uint4* __restrict__ zero8k) {
    __shared__ float tile[128][33];
    __shared__ float ered[2];
    const int j = blockIdx.x;                        // doubles as code id
    const int t = threadIdx.x;
    if (t < 128) {                                   // e-cvt for code j
        float a = embed[(size_t)j * K_ + t];
        eh[(size_t)j * K_ + t] = (f16)(-2.f * a);
        float s = a * a;
        #pragma unroll
        for (int off = 32; off; off >>= 1) s += __shfl_down(s, off);
        if ((t & 63) == 0) ered[t >> 6] = s;
    }
    if (j < 2) zero8k[j * 256 + t] = make_uint4(0u, 0u, 0u, 0u);

    int b = j >> 5, h = j & 31;
    const size_t base = (size_t)b * 131072 + (size_t)h * 32;
    #pragma unroll
    for (int i = 0; i < 4; ++i) {                    // 1024 float4 loads
        int q = i * 256 + t;
        int c = q >> 3, w4 = (q & 7) * 4;
        float4 v = *(const float4*)(ze + base + (size_t)c * 1024 + w4);
        tile[c][w4 + 0] = v.x; tile[c][w4 + 1] = v.y;
        tile[c][w4 + 2] = v.z; tile[c][w4 + 3] = v.w;
        *(float4*)(out_ze + base + (size_t)c * 1024 + w4) = v;
    }
    __syncthreads();
    if (t == 0) nl[j] = ered[0] + ered[1];
    const int r0 = b * 1024 + h * 32;
    #pragma unroll
    for (int i = 0; i < 2; ++i) {                    // 8-wide row spans
        int w = (t >> 4) + i * 16;
        int c0 = (t & 15) * 8;
        int r = r0 + w;
        float vv[8];
        #pragma unroll
        for (int q = 0; q < 8; ++q) vv[q] = tile[c0 + q][w];
        *(float4*)(flat + (size_t)r * K_ + c0)     = make_float4(vv[0], vv[1], vv[2], vv[3]);
        *(float4*)(flat + (size_t)r * K_ + c0 + 4) = make_float4(vv[4], vv[5], vv[6], vv[7]);
        f16x8 hv;
        #pragma unroll
        for (int q = 0; q < 8; ++q) hv[q] = (f16)vv[q];
        size_t xa = (size_t)r * K_ + ((((c0 >> 3) ^ (r & 15)) << 3));
        *(f16x8*)(xh + xa) = hv;
    }
}

// MFMA NN search — r13 grid (128,4), but DOUBLE-BUFFERED x staging with the
// stage issued at iteration top (before compute): loads hide under the ~5K-cy
// MFMA+fold phase instead of the ~200-cy merge (r13 single-buffer exposed the
// global->LDS latency at the loop-end vmcnt(0) drain 4x/block — T14/G15).
// LDS 36.25KB -> still 4 blocks/CU at (256,4).
__global__ __launch_bounds__(256, 4)
void nn_kernel(const f16* __restrict__ xh_g,
               const f16* __restrict__ eh, const float* __restrict__ nl,
               uint4* __restrict__ p_pk) {
    __shared__ __align__(16) f16 xbh[2][64 * 128];   // 32KB double buffer
    __shared__ uint4 pm[4][64];                      // 4KB packed merge
    const int t = threadIdx.x;
    const int wave = t >> 6, lane = t & 63;
    const int crow = lane & 15, g = lane >> 4;
    const int c0 = blockIdx.y * 256 + wave * 64;

    f16x8 efh[4][4];                                 // 64 VGPR persistent
    #pragma unroll
    for (int m = 0; m < 4; ++m)
        #pragma unroll
        for (int kt = 0; kt < 4; ++kt)
            efh[m][kt] = *(const f16x8*)(eh + (size_t)(c0 + m * 16 + crow) * K_ + kt * 32 + g * 8);
    f32x4 nlinit[4];
    #pragma unroll
    for (int m = 0; m < 4; ++m) {
        f32x4 v = *(const f32x4*)(nl + c0 + m * 16 + g * 4);
        nlinit[m] = v + 1024.f;                      // (acc)*1024 = s*1024 + 2^20
    }
    const unsigned cbase = (unsigned)(c0 + g * 4);

    auto stage = [&](int bt, int db) {
        const size_t tb = (size_t)(blockIdx.x * 4 + bt) * 8192;
        #pragma unroll
        for (int i = 0; i < 4; ++i) {
            int q = wave * 4 + i;                    // 16 x 1KB chunks
            GLOAD_LDS(xh_g + tb + q * 512 + lane * 8, &xbh[db][q * 512]);
        }
    };

    stage(0, 0);
    __syncthreads();                                 // buf0 ready
    for (int bt = 0; bt < 4; ++bt) {
        const int db = bt & 1;
        const int R0 = (blockIdx.x * 4 + bt) * 64;
        if (bt < 3) stage(bt + 1, db ^ 1);           // loads fly under compute
        #pragma unroll
        for (int st = 0; st < 4; ++st) {
            f32x4 acc[4];
            #pragma unroll
            for (int m = 0; m < 4; ++m) acc[m] = nlinit[m];
            #pragma unroll
            for (int kt = 0; kt < 4; ++kt) {
                int off = (st * 16 + crow) * 128 + ((((kt << 2) + g) ^ crow) << 3);
                f16x8 bh = *(const f16x8*)&xbh[db][off];
                #pragma unroll
                for (int m = 0; m < 4; ++m)
                    acc[m] = __builtin_amdgcn_mfma_f32_16x16x32_f16(efh[m][kt], bh, acc[m], 0, 0, 0);
            }
            unsigned m1 = ~0u, m2 = ~0u, m3 = ~0u;
            #pragma unroll
            for (int m = 0; m < 4; ++m)
                #pragma unroll
                for (int q = 0; q < 4; ++q) {
                    unsigned u = (unsigned)(acc[m][q] * 1024.f);
                    unsigned p = (u << 10) + cbase + (unsigned)(m * 16 + q);
                    PINS(p);
                }
            #pragma unroll
            for (int d = 16; d <= 32; d <<= 1) {     // merge 4 lane-groups per row
                unsigned o1 = (unsigned)__shfl_xor((int)m1, d);
                unsigned o2 = (unsigned)__shfl_xor((int)m2, d);
                unsigned o3 = (unsigned)__shfl_xor((int)m3, d);
                PINS(o1); PINS(o2); PINS(o3);
            }
            if (lane < 16) pm[wave][st * 16 + crow] = make_uint4(m1, m2, m3, 0u);
        }
        __syncthreads();                             // pm ready (stage loads drained, hidden)
        if (lane < 16) {                             // each wave merges 16 rows
            int row = wave * 16 + lane;
            uint4 a = pm[0][row];
            unsigned m1 = a.x, m2 = a.y, m3 = a.z;
            #pragma unroll
            for (int w = 1; w < 4; ++w) {
                uint4 b = pm[w][row];
                PINS(b.x); PINS(b.y); PINS(b.z);
            }
            p_pk[(size_t)blockIdx.y * M_ + R0 + row] = make_uint4(m1, m2, m3, 0u);
        }
        __syncthreads();                             // merge done; pm + other buf reusable
    }
}

// merge 4 split top-3s; exact fp32 recompute of the 3 candidates ONLY when the
// quantized gap <= 0.5 (~4% of rows; round-11 branchless variant cost +13us).
__global__ void reduce_refine_kernel(const uint4* __restrict__ p_pk,
                                     const float* __restrict__ flat,
                                     const float* __restrict__ embed,
                                     const float* __restrict__ nl,
                                     int* __restrict__ idxws, float* __restrict__ out_idx,
                                     int* __restrict__ counts) {
    int r = blockIdx.x * 256 + threadIdx.x;
    uint4 a = p_pk[r];
    unsigned m1 = a.x, m2 = a.y, m3 = a.z;
    #pragma unroll
    for (int y = 1; y < 4; ++y) {
        uint4 b = p_pk[(size_t)y * M_ + r];
        PINS(b.x); PINS(b.y); PINS(b.z);
    }
    int i1 = (int)(m1 & 1023u);
    if ((m2 >> 10) - (m1 >> 10) <= 512u) {
        int i2 = (int)(m2 & 1023u), i3 = (int)(m3 & 1023u);
        const float* x  = flat  + (size_t)r * K_;
        const float* e1 = embed + (size_t)i1 * K_;
        const float* e2 = embed + (size_t)i2 * K_;
        const float* e3 = embed + (size_t)i3 * K_;
        float d1 = 0.f, d2 = 0.f, d3 = 0.f;
        for (int k = 0; k < K_; ++k) {
            float xv = x[k];
            d1 = fmaf(xv, e1[k], d1);
            d2 = fmaf(xv, e2[k], d2);
            d3 = fmaf(xv, e3[k], d3);
        }
        float s1 = fmaf(-2.f, d1, nl[i1]);
        float s2 = fmaf(-2.f, d2, nl[i2]);
        float s3 = fmaf(-2.f, d3, nl[i3]);
        float bs = s1; int bi = i1;
        if (s2 < bs || (s2 == bs && i2 < bi)) { bs = s2; bi = i2; }
        if (s3 < bs || (s3 == bs && i3 < bi)) { bs = s3; bi = i3; }
        i1 = bi;
    }
    idxws[r] = i1;
    out_idx[r] = (float)i1;
    atomicAdd(counts + i1, 1);
}

// pure gather: z_q_st == z_q to 1 ulp (z_e + (z_q - z_e)); no z_e read, no loss.
__global__ void gather_kernel(const float* __restrict__ embed,
                              const int* __restrict__ idxws,
                              float* __restrict__ out_st, float* __restrict__ out_zq) {
    int q = blockIdx.x * 256 + threadIdx.x;
    int o0 = q * 4;
    int rbase = (o0 >> 17) * 1024 + (o0 & 1023);
    int c = (o0 >> 10) & 127;
    int4 jj = *(const int4*)(idxws + rbase);         // r..r+3 contiguous
    float4 zq = make_float4(embed[(size_t)jj.x * K_ + c], embed[(size_t)jj.y * K_ + c],
                            embed[(size_t)jj.z * K_ + c], embed[(size_t)jj.w * K_ + c]);
    *(float4*)(out_st + o0) = zq;
    *(float4*)(out_zq + o0) = zq;
}

// new_cluster_size + its sum + exclusive scan of counts (bucket offsets).
// Separate kernel (round-15 A/B: last-block fusion with threadfence cost +2us).
__global__ void ema_a_kernel(const float* __restrict__ cluster_size,
                             const int* __restrict__ counts,
                             float* __restrict__ out_ncs, float* __restrict__ nws,
                             int* __restrict__ offs) {
    int j = threadIdx.x;                       // 1024 threads
    int cnt = counts[j];
    float ncs = cluster_size[j] * DECAY + ONE_MINUS_DECAY * (float)cnt;
    out_ncs[j] = ncs;
    __shared__ float red[1024];
    __shared__ int sc[1024];
    red[j] = ncs;
    sc[j] = cnt;
    __syncthreads();
    for (int d = 1; d < 1024; d <<= 1) {       // Hillis-Steele inclusive scan
        int v = (j >= d) ? sc[j - d] : 0;
        __syncthreads();
        sc[j] += v;
        __syncthreads();
    }
    offs[j] = sc[j] - cnt;
    for (int st = 512; st; st >>= 1) {
        if (j < st) red[j] += red[j + st];
        __syncthreads();
    }
    if (j == 0) nws[0] = red[0];
}

// scatter row ids into per-code buckets; LDS-histogram pre-aggregation keeps
// global atomic depth per code <= #blocks regardless of cluster skew.
// Also zeroes esum (512KB) for chunksum (kernel-boundary ordering).
__global__ void bucket_kernel(const int* __restrict__ idxws, const int* __restrict__ offs,
                              int* __restrict__ cur, int* __restrict__ rows,
                              float4* __restrict__ esum_z) {
    __shared__ int lcnt[N_];
    __shared__ int lbase[N_];
    int t = threadIdx.x;                       // 256
    esum_z[blockIdx.x * 256 + t] = make_float4(0.f, 0.f, 0.f, 0.f);
    #pragma unroll
    for (int i = 0; i < 4; ++i) lcnt[i * 256 + t] = 0;
    __syncthreads();
    int r = blockIdx.x * 256 + t;
    int j = idxws[r];
    atomicAdd(&lcnt[j], 1);                    // LDS atomic
    __syncthreads();
    #pragma unroll
    for (int i = 0; i < 4; ++i) {
        int c = i * 256 + t;
        int n = lcnt[c];
        lbase[c] = n ? atomicAdd(cur + c, n) : 0;
        lcnt[c] = 0;
    }
    __syncthreads();
    int p = atomicAdd(&lcnt[j], 1) + lbase[j];
    rows[offs[j] + p] = r;
}

// load-balanced segmented sum + loss: 64 sorted rows per block; one esum atomic
// per code-segment boundary; loss = sum (x - e_code)^2 accumulated per-thread
// (coalesced e reads, L2-hot) -> one double partial per block.
__global__ void chunksum_kernel(const float* __restrict__ flat,
                                const float* __restrict__ embed,
                                const int* __restrict__ rows,
                                const int* __restrict__ idxws,
                                float* __restrict__ esum,
                                double* __restrict__ lpart) {
    __shared__ int srid[64];
    __shared__ int scd[65];
    __shared__ double lred[128];
    int k = threadIdx.x;                       // 128 threads = K dim
    int b = blockIdx.x;                        // 512 chunks
    if (k < 64) {
        int r = rows[b * 64 + k];
        srid[k] = r;
        scd[k] = idxws[r];
    }
    if (k == 64) scd[64] = -1;                 // sentinel != any code
    __syncthreads();
    float acc = 0.f;
    double lacc = 0.0;
    #pragma unroll 1
    for (int i0 = 0; i0 < 64; i0 += 8) {
        float v[8], ev[8];
        #pragma unroll
        for (int i = 0; i < 8; ++i)
            v[i] = flat[(size_t)srid[i0 + i] * K_ + k];          // 8 independent loads
        #pragma unroll
        for (int i = 0; i < 8; ++i)
            ev[i] = embed[(size_t)scd[i0 + i] * K_ + k];         // coalesced, L2-hot
        #pragma unroll
        for (int i = 0; i < 8; ++i) {
            acc += v[i];
            float diff = ev[i] - v[i];
            lacc = fmaf((double)diff, (double)diff, lacc);
            int p = i0 + i;
            if (scd[p + 1] != scd[p]) {        // wave-uniform branch
                atomicAdd(esum + (size_t)scd[p] * K_ + k, acc);
                acc = 0.f;
            }
        }
    }
    lred[k] = lacc;
    __syncthreads();
    for (int s = 64; s; s >>= 1) {
        if (k < s) lred[k] += lred[k + s];
        __syncthreads();
    }
    if (k == 0) lpart[b] = lred[0];
}

// EMA + normalize epilogue on esum; block 0 also finalizes the loss from
// chunksum's 512 partials (runs after chunksum -> no cross-call state).
__global__ void ema_b_kernel(const float* __restrict__ embed_avg,
                             const float* __restrict__ esum,
                             const float* __restrict__ out_ncs,
                             const float* __restrict__ nws,
                             const double* __restrict__ lpart,
                             float* __restrict__ out_nea, float* __restrict__ out_emb,
                             float* __restrict__ out_loss) {
    int o = blockIdx.x * 256 + threadIdx.x;
    int j = o >> 7;
    float navg = embed_avg[o] * DECAY + ONE_MINUS_DECAY * esum[o];
    out_nea[o] = navg;
    float n = nws[0];
    float denom = n + 1024.0f * EPSF;
    float cs = (out_ncs[j] + EPSF) / denom * n;
    float cs_safe = fmaxf(cs, EPSF);
    float v = navg / cs_safe;
    if (v != v) v = 0.f;
    v = fminf(fmaxf(v, -2.f), 2.f);
    out_emb[o] = v;
    if (blockIdx.x == 0) {
        __shared__ double red[256];
        int t = threadIdx.x;
        red[t] = lpart[t] + lpart[t + 256];
        __syncthreads();
        for (int s = 128; s; s >>= 1) {
            if (t < s) red[t] += red[t + s];
            __syncthreads();
        }
        if (t == 0) out_loss[0] = (float)((double)BETA * (red[0] / 4194304.0));
    }
}

extern "C" void kernel_launch(void* const* d_in, const int* in_sizes, int n_in,
                              void* d_out, int out_size, void* d_ws, size_t ws_size,
                              hipStream_t stream) {
    const float* z_e          = (const float*)d_in[0];
    const float* embed        = (const float*)d_in[1];
    const float* cluster_size = (const float*)d_in[2];
    const float* embed_avg    = (const float*)d_in[3];
    float* out = (float*)d_out;
    char*  ws  = (char*)d_ws;

    float*  flat   = (float*)(ws + WS_FLAT);
    f16*    xhp    = (f16*)  (ws + WS_XH);
    f16*    ehp    = (f16*)  (ws + WS_EH);
    float*  nlp    = (float*)(ws + WS_NL);
    uint4*  p_pk   = (uint4*)(ws + WS_PPK);
    int*    idxws  = (int*)  (ws + WS_IDX);
    int*    counts = (int*)  (ws + WS_COUNTS);
    int*    cur    = (int*)  (ws + WS_CUR);
    float*  esum   = (float*)(ws + WS_ESUM);
    int*    offs   = (int*)  (ws + WS_OFFS);
    int*    rows   = (int*)  (ws + WS_ROWS);
    double* lpart  = (double*)(ws + WS_LPART);
    float*  nws    = (float*)(ws + WS_NSUM);

    transpose_kernel<<<1024, 256, 0, stream>>>(z_e, embed, flat, xhp, out + O_ZE,
                                               ehp, nlp, (uint4*)(ws + WS_COUNTS));
    nn_kernel<<<dim3(128, 4), 256, 0, stream>>>(xhp, ehp, nlp, p_pk);
    reduce_refine_kernel<<<M_ / 256, 256, 0, stream>>>(p_pk, flat, embed, nlp,
                                                       idxws, out + O_IDX, counts);
    gather_kernel<<<4096, 256, 0, stream>>>(embed, idxws, out + O_ZQST, out + O_ZQ);
    ema_a_kernel<<<1, 1024, 0, stream>>>(cluster_size, counts, out + O_NCS, nws, offs);
    bucket_kernel<<<M_ / 256, 256, 0, stream>>>(idxws, offs, cur, rows,
                                                (float4*)(ws + WS_ESUM));
    chunksum_kernel<<<M_ / 64, K_, 0, stream>>>(flat, embed, rows, idxws, esum, lpart);
    ema_b_kernel<<<(N_ * K_) / 256, 256, 0, stream>>>(embed_avg, esum, out + O_NCS, nws,
                                                      lpart, out + O_NEA, out + O_EMB,
                                                      out + O_LOSS);
}

// Round 17
// 91.860 us; speedup vs baseline: 1.0373x; 1.0205x over previous
//
#include <hip/hip_runtime.h>

#define DECAY 0.99f
#define ONE_MINUS_DECAY 0.01f
#define EPSF 1e-5f
#define BETA 0.25f

constexpr int M_ = 32768;            // rows (B*H*W)
constexpr int N_ = 1024;             // codes
constexpr int K_ = 128;              // dim

typedef _Float16 f16;
typedef f16 f16x8 __attribute__((ext_vector_type(8)));
typedef float f32x4 __attribute__((ext_vector_type(4)));

#define GLOAD_LDS(g, l) __builtin_amdgcn_global_load_lds( \
    (const __attribute__((address_space(1))) void*)(g),   \
    (__attribute__((address_space(3))) void*)(l), 16, 0, 0)

// packed top-3 insert: (score<<10)|idx, unsigned order == (score, idx) lexicographic
#define PINS(p) { unsigned _t2 = m1 > (p) ? m1 : (p); m1 = m1 < (p) ? m1 : (p); \
                  unsigned _t3 = m2 > _t2 ? m2 : _t2;  m2 = m2 < _t2 ? m2 : _t2; \
                  m3 = m3 < _t3 ? m3 : _t3; }

// ---- workspace layout (bytes) ----
constexpr size_t WS_FLAT   = 0;                                   // M*K fp32 (16MB)
constexpr size_t WS_XH     = WS_FLAT   + (size_t)M_ * K_ * 4;     // M*K f16, tile-swizzled
constexpr size_t WS_EH     = WS_XH     + (size_t)M_ * K_ * 2;     // N*K f16 (-2e)
constexpr size_t WS_NL     = WS_EH     + (size_t)N_ * K_ * 2;     // N fp32 ||e||^2
constexpr size_t WS_PPK    = WS_NL     + (size_t)N_ * 4;          // 4*M uint4 packed top-3
constexpr size_t WS_IDX    = WS_PPK    + (size_t)4 * M_ * 16;     // M int
constexpr size_t WS_COUNTS = WS_IDX    + (size_t)M_ * 4;          // N int  (zeroed in transpose)
constexpr size_t WS_CUR    = WS_COUNTS + (size_t)N_ * 4;          // N int  (zeroed in transpose)
constexpr size_t WS_ESUM   = WS_CUR    + (size_t)N_ * 4;          // N*K f32 (zeroed in bucket)
constexpr size_t WS_OFFS   = WS_ESUM   + (size_t)N_ * K_ * 4;     // N int
constexpr size_t WS_ROWS   = WS_OFFS   + (size_t)N_ * 4;          // M int
constexpr size_t WS_LPART  = WS_ROWS   + (size_t)M_ * 4;          // 512 doubles (chunksum)
constexpr size_t WS_NSUM   = WS_LPART  + (size_t)4096 * 8;        // 1 float

// ---- output layout (float elements) ----
constexpr size_t O_ZQST = 0;
constexpr size_t O_LOSS = O_ZQST + (size_t)M_ * K_;
constexpr size_t O_IDX  = O_LOSS + 1;
constexpr size_t O_ZQ   = O_IDX  + (size_t)M_;
constexpr size_t O_ZE   = O_ZQ   + (size_t)M_ * K_;
constexpr size_t O_EMB  = O_ZE   + (size_t)M_ * K_;
constexpr size_t O_NCS  = O_EMB  + (size_t)N_ * K_;
constexpr size_t O_NEA  = O_NCS  + (size_t)N_;

// (B,C,H,W) -> flat[r][c] fp32 + xh f16 tile-swizzled + z_e out.
// Fused: block j converts code j (eh, nl); blocks 0-1 zero counts+cur.
__global__ void transpose_kernel(const float* __restrict__ ze,
                                 const float* __restrict__ embed,
                                 float* __restrict__ flat,
                                 f16* __restrict__ xh,
                                 float* __restrict__ out_ze,
                                 f16* __restrict__ eh, float* __restrict__ nl,
                                 uint4* __restrict__ zero8k) {
    __shared__ float tile[128][33];
    __shared__ float ered[2];
    const int j = blockIdx.x;                        // doubles as code id
    const int t = threadIdx.x;
    if (t < 128) {                                   // e-cvt for code j
        float a = embed[(size_t)j * K_ + t];
        eh[(size_t)j * K_ + t] = (f16)(-2.f * a);
        float s = a * a;
        #pragma unroll
        for (int off = 32; off; off >>= 1) s += __shfl_down(s, off);
        if ((t & 63) == 0) ered[t >> 6] = s;
    }
    if (j < 2) zero8k[j * 256 + t] = make_uint4(0u, 0u, 0u, 0u);

    int b = j >> 5, h = j & 31;
    const size_t base = (size_t)b * 131072 + (size_t)h * 32;
    #pragma unroll
    for (int i = 0; i < 4; ++i) {                    // 1024 float4 loads
        int q = i * 256 + t;
        int c = q >> 3, w4 = (q & 7) * 4;
        float4 v = *(const float4*)(ze + base + (size_t)c * 1024 + w4);
        tile[c][w4 + 0] = v.x; tile[c][w4 + 1] = v.y;
        tile[c][w4 + 2] = v.z; tile[c][w4 + 3] = v.w;
        *(float4*)(out_ze + base + (size_t)c * 1024 + w4) = v;
    }
    __syncthreads();
    if (t == 0) nl[j] = ered[0] + ered[1];
    const int r0 = b * 1024 + h * 32;
    #pragma unroll
    for (int i = 0; i < 2; ++i) {                    // 8-wide row spans
        int w = (t >> 4) + i * 16;
        int c0 = (t & 15) * 8;
        int r = r0 + w;
        float vv[8];
        #pragma unroll
        for (int q = 0; q < 8; ++q) vv[q] = tile[c0 + q][w];
        *(float4*)(flat + (size_t)r * K_ + c0)     = make_float4(vv[0], vv[1], vv[2], vv[3]);
        *(float4*)(flat + (size_t)r * K_ + c0 + 4) = make_float4(vv[4], vv[5], vv[6], vv[7]);
        f16x8 hv;
        #pragma unroll
        for (int q = 0; q < 8; ++q) hv[q] = (f16)vv[q];
        size_t xa = (size_t)r * K_ + ((((c0 >> 3) ^ (r & 15)) << 3));
        *(f16x8*)(xh + xa) = hv;
    }
}

// MFMA NN search — round-13 proven config (91.9us): grid (128,4), 4 x-tiles
// per block, SINGLE-buffered staging issued after the compute barrier (hides
// under the merge phase; r16's explicit dbuf was neutral -> m97 lesson, the
// implicit wave overlap at 4 blocks/CU already hides staging). Single-f16 x/e;
// packed fixed-point top-3 per row; exact fp32 re-rank in refine.
__global__ __launch_bounds__(256, 4)
void nn_kernel(const f16* __restrict__ xh_g,
               const f16* __restrict__ eh, const float* __restrict__ nl,
               uint4* __restrict__ p_pk) {
    __shared__ __align__(16) f16 xbh[64 * 128];      // 16KB
    __shared__ uint4 pm[4][64];                      // 4KB packed merge
    const int t = threadIdx.x;
    const int wave = t >> 6, lane = t & 63;
    const int crow = lane & 15, g = lane >> 4;
    const int c0 = blockIdx.y * 256 + wave * 64;

    f16x8 efh[4][4];                                 // 64 VGPR persistent
    #pragma unroll
    for (int m = 0; m < 4; ++m)
        #pragma unroll
        for (int kt = 0; kt < 4; ++kt)
            efh[m][kt] = *(const f16x8*)(eh + (size_t)(c0 + m * 16 + crow) * K_ + kt * 32 + g * 8);
    f32x4 nlinit[4];
    #pragma unroll
    for (int m = 0; m < 4; ++m) {
        f32x4 v = *(const f32x4*)(nl + c0 + m * 16 + g * 4);
        nlinit[m] = v + 1024.f;                      // (acc)*1024 = s*1024 + 2^20
    }
    const unsigned cbase = (unsigned)(c0 + g * 4);

    auto stage = [&](int bt) {
        const size_t tb = (size_t)(blockIdx.x * 4 + bt) * 8192;
        #pragma unroll
        for (int i = 0; i < 4; ++i) {
            int q = wave * 4 + i;                    // 16 x 1KB chunks
            GLOAD_LDS(xh_g + tb + q * 512 + lane * 8, &xbh[q * 512]);
        }
    };

    stage(0);
    __syncthreads();                                 // vmcnt drained -> xb ready
    for (int bt = 0; bt < 4; ++bt) {
        const int R0 = (blockIdx.x * 4 + bt) * 64;
        #pragma unroll
        for (int st = 0; st < 4; ++st) {
            f32x4 acc[4];
            #pragma unroll
            for (int m = 0; m < 4; ++m) acc[m] = nlinit[m];
            #pragma unroll
            for (int kt = 0; kt < 4; ++kt) {
                int off = (st * 16 + crow) * 128 + ((((kt << 2) + g) ^ crow) << 3);
                f16x8 bh = *(const f16x8*)&xbh[off];
                #pragma unroll
                for (int m = 0; m < 4; ++m)
                    acc[m] = __builtin_amdgcn_mfma_f32_16x16x32_f16(efh[m][kt], bh, acc[m], 0, 0, 0);
            }
            unsigned m1 = ~0u, m2 = ~0u, m3 = ~0u;
            #pragma unroll
            for (int m = 0; m < 4; ++m)
                #pragma unroll
                for (int q = 0; q < 4; ++q) {
                    unsigned u = (unsigned)(acc[m][q] * 1024.f);
                    unsigned p = (u << 10) + cbase + (unsigned)(m * 16 + q);
                    PINS(p);
                }
            #pragma unroll
            for (int d = 16; d <= 32; d <<= 1) {     // merge 4 lane-groups per row
                unsigned o1 = (unsigned)__shfl_xor((int)m1, d);
                unsigned o2 = (unsigned)__shfl_xor((int)m2, d);
                unsigned o3 = (unsigned)__shfl_xor((int)m3, d);
                PINS(o1); PINS(o2); PINS(o3);
            }
            if (lane < 16) pm[wave][st * 16 + crow] = make_uint4(m1, m2, m3, 0u);
        }
        __syncthreads();                             // xb consumed + pm ready
        if (bt < 3) stage(bt + 1);                   // async loads fly under merge
        if (lane < 16) {                             // each wave merges 16 rows
            int row = wave * 16 + lane;
            uint4 a = pm[0][row];
            unsigned m1 = a.x, m2 = a.y, m3 = a.z;
            #pragma unroll
            for (int w = 1; w < 4; ++w) {
                uint4 b = pm[w][row];
                PINS(b.x); PINS(b.y); PINS(b.z);
            }
            p_pk[(size_t)blockIdx.y * M_ + R0 + row] = make_uint4(m1, m2, m3, 0u);
        }
        __syncthreads();                             // vmcnt drain; pm reusable
    }
}

// merge 4 split top-3s; exact fp32 recompute of the 3 candidates ONLY when the
// quantized gap <= 0.5 (~4% of rows; round-11 branchless variant cost +13us).
__global__ void reduce_refine_kernel(const uint4* __restrict__ p_pk,
                                     const float* __restrict__ flat,
                                     const float* __restrict__ embed,
                                     const float* __restrict__ nl,
                                     int* __restrict__ idxws, float* __restrict__ out_idx,
                                     int* __restrict__ counts) {
    int r = blockIdx.x * 256 + threadIdx.x;
    uint4 a = p_pk[r];
    unsigned m1 = a.x, m2 = a.y, m3 = a.z;
    #pragma unroll
    for (int y = 1; y < 4; ++y) {
        uint4 b = p_pk[(size_t)y * M_ + r];
        PINS(b.x); PINS(b.y); PINS(b.z);
    }
    int i1 = (int)(m1 & 1023u);
    if ((m2 >> 10) - (m1 >> 10) <= 512u) {
        int i2 = (int)(m2 & 1023u), i3 = (int)(m3 & 1023u);
        const float* x  = flat  + (size_t)r * K_;
        const float* e1 = embed + (size_t)i1 * K_;
        const float* e2 = embed + (size_t)i2 * K_;
        const float* e3 = embed + (size_t)i3 * K_;
        float d1 = 0.f, d2 = 0.f, d3 = 0.f;
        for (int k = 0; k < K_; ++k) {
            float xv = x[k];
            d1 = fmaf(xv, e1[k], d1);
            d2 = fmaf(xv, e2[k], d2);
            d3 = fmaf(xv, e3[k], d3);
        }
        float s1 = fmaf(-2.f, d1, nl[i1]);
        float s2 = fmaf(-2.f, d2, nl[i2]);
        float s3 = fmaf(-2.f, d3, nl[i3]);
        float bs = s1; int bi = i1;
        if (s2 < bs || (s2 == bs && i2 < bi)) { bs = s2; bi = i2; }
        if (s3 < bs || (s3 == bs && i3 < bi)) { bs = s3; bi = i3; }
        i1 = bi;
    }
    idxws[r] = i1;
    out_idx[r] = (float)i1;
    atomicAdd(counts + i1, 1);
}

// pure gather: z_q_st == z_q to 1 ulp (z_e + (z_q - z_e)); no z_e read, no loss.
__global__ void gather_kernel(const float* __restrict__ embed,
                              const int* __restrict__ idxws,
                              float* __restrict__ out_st, float* __restrict__ out_zq) {
    int q = blockIdx.x * 256 + threadIdx.x;
    int o0 = q * 4;
    int rbase = (o0 >> 17) * 1024 + (o0 & 1023);
    int c = (o0 >> 10) & 127;
    int4 jj = *(const int4*)(idxws + rbase);         // r..r+3 contiguous
    float4 zq = make_float4(embed[(size_t)jj.x * K_ + c], embed[(size_t)jj.y * K_ + c],
                            embed[(size_t)jj.z * K_ + c], embed[(size_t)jj.w * K_ + c]);
    *(float4*)(out_st + o0) = zq;
    *(float4*)(out_zq + o0) = zq;
}

// new_cluster_size + its sum + exclusive scan of counts (bucket offsets).
// Separate kernel (round-15 A/B: last-block fusion with threadfence cost +2us).
__global__ void ema_a_kernel(const float* __restrict__ cluster_size,
                             const int* __restrict__ counts,
                             float* __restrict__ out_ncs, float* __restrict__ nws,
                             int* __restrict__ offs) {
    int j = threadIdx.x;                       // 1024 threads
    int cnt = counts[j];
    float ncs = cluster_size[j] * DECAY + ONE_MINUS_DECAY * (float)cnt;
    out_ncs[j] = ncs;
    __shared__ float red[1024];
    __shared__ int sc[1024];
    red[j] = ncs;
    sc[j] = cnt;
    __syncthreads();
    for (int d = 1; d < 1024; d <<= 1) {       // Hillis-Steele inclusive scan
        int v = (j >= d) ? sc[j - d] : 0;
        __syncthreads();
        sc[j] += v;
        __syncthreads();
    }
    offs[j] = sc[j] - cnt;
    for (int st = 512; st; st >>= 1) {
        if (j < st) red[j] += red[j + st];
        __syncthreads();
    }
    if (j == 0) nws[0] = red[0];
}

// scatter row ids into per-code buckets; LDS-histogram pre-aggregation keeps
// global atomic depth per code <= #blocks regardless of cluster skew.
// Also zeroes esum (512KB) for chunksum (kernel-boundary ordering).
__global__ void bucket_kernel(const int* __restrict__ idxws, const int* __restrict__ offs,
                              int* __restrict__ cur, int* __restrict__ rows,
                              float4* __restrict__ esum_z) {
    __shared__ int lcnt[N_];
    __shared__ int lbase[N_];
    int t = threadIdx.x;                       // 256
    esum_z[blockIdx.x * 256 + t] = make_float4(0.f, 0.f, 0.f, 0.f);
    #pragma unroll
    for (int i = 0; i < 4; ++i) lcnt[i * 256 + t] = 0;
    __syncthreads();
    int r = blockIdx.x * 256 + t;
    int j = idxws[r];
    atomicAdd(&lcnt[j], 1);                    // LDS atomic
    __syncthreads();
    #pragma unroll
    for (int i = 0; i < 4; ++i) {
        int c = i * 256 + t;
        int n = lcnt[c];
        lbase[c] = n ? atomicAdd(cur + c, n) : 0;
        lcnt[c] = 0;
    }
    __syncthreads();
    int p = atomicAdd(&lcnt[j], 1) + lbase[j];
    rows[offs[j] + p] = r;
}

// load-balanced segmented sum + loss: 64 sorted rows per block; one esum atomic
// per code-segment boundary; loss = sum (x - e_code)^2 accumulated per-thread
// (coalesced e reads, L2-hot) -> one double partial per block.
__global__ void chunksum_kernel(const float* __restrict__ flat,
                                const float* __restrict__ embed,
                                const int* __restrict__ rows,
                                const int* __restrict__ idxws,
                                float* __restrict__ esum,
                                double* __restrict__ lpart) {
    __shared__ int srid[64];
    __shared__ int scd[65];
    __shared__ double lred[128];
    int k = threadIdx.x;                       // 128 threads = K dim
    int b = blockIdx.x;                        // 512 chunks
    if (k < 64) {
        int r = rows[b * 64 + k];
        srid[k] = r;
        scd[k] = idxws[r];
    }
    if (k == 64) scd[64] = -1;                 // sentinel != any code
    __syncthreads();
    float acc = 0.f;
    double lacc = 0.0;
    #pragma unroll 1
    for (int i0 = 0; i0 < 64; i0 += 8) {
        float v[8], ev[8];
        #pragma unroll
        for (int i = 0; i < 8; ++i)
            v[i] = flat[(size_t)srid[i0 + i] * K_ + k];          // 8 independent loads
        #pragma unroll
        for (int i = 0; i < 8; ++i)
            ev[i] = embed[(size_t)scd[i0 + i] * K_ + k];         // coalesced, L2-hot
        #pragma unroll
        for (int i = 0; i < 8; ++i) {
            acc += v[i];
            float diff = ev[i] - v[i];
            lacc = fmaf((double)diff, (double)diff, lacc);
            int p = i0 + i;
            if (scd[p + 1] != scd[p]) {        // wave-uniform branch
                atomicAdd(esum + (size_t)scd[p] * K_ + k, acc);
                acc = 0.f;
            }
        }
    }
    lred[k] = lacc;
    __syncthreads();
    for (int s = 64; s; s >>= 1) {
        if (k < s) lred[k] += lred[k + s];
        __syncthreads();
    }
    if (k == 0) lpart[b] = lred[0];
}

// EMA + normalize epilogue on esum; block 0 also finalizes the loss from
// chunksum's 512 partials (runs after chunksum -> no cross-call state).
__global__ void ema_b_kernel(const float* __restrict__ embed_avg,
                             const float* __restrict__ esum,
                             const float* __restrict__ out_ncs,
                             const float* __restrict__ nws,
                             const double* __restrict__ lpart,
                             float* __restrict__ out_nea, float* __restrict__ out_emb,
                             float* __restrict__ out_loss) {
    int o = blockIdx.x * 256 + threadIdx.x;
    int j = o >> 7;
    float navg = embed_avg[o] * DECAY + ONE_MINUS_DECAY * esum[o];
    out_nea[o] = navg;
    float n = nws[0];
    float denom = n + 1024.0f * EPSF;
    float cs = (out_ncs[j] + EPSF) / denom * n;
    float cs_safe = fmaxf(cs, EPSF);
    float v = navg / cs_safe;
    if (v != v) v = 0.f;
    v = fminf(fmaxf(v, -2.f), 2.f);
    out_emb[o] = v;
    if (blockIdx.x == 0) {
        __shared__ double red[256];
        int t = threadIdx.x;
        red[t] = lpart[t] + lpart[t + 256];
        __syncthreads();
        for (int s = 128; s; s >>= 1) {
            if (t < s) red[t] += red[t + s];
            __syncthreads();
        }
        if (t == 0) out_loss[0] = (float)((double)BETA * (red[0] / 4194304.0));
    }
}

extern "C" void kernel_launch(void* const* d_in, const int* in_sizes, int n_in,
                              void* d_out, int out_size, void* d_ws, size_t ws_size,
                              hipStream_t stream) {
    const float* z_e          = (const float*)d_in[0];
    const float* embed        = (const float*)d_in[1];
    const float* cluster_size = (const float*)d_in[2];
    const float* embed_avg    = (const float*)d_in[3];
    float* out = (float*)d_out;
    char*  ws  = (char*)d_ws;

    float*  flat   = (float*)(ws + WS_FLAT);
    f16*    xhp    = (f16*)  (ws + WS_XH);
    f16*    ehp    = (f16*)  (ws + WS_EH);
    float*  nlp    = (float*)(ws + WS_NL);
    uint4*  p_pk   = (uint4*)(ws + WS_PPK);
    int*    idxws  = (int*)  (ws + WS_IDX);
    int*    counts = (int*)  (ws + WS_COUNTS);
    int*    cur    = (int*)  (ws + WS_CUR);
    float*  esum   = (float*)(ws + WS_ESUM);
    int*    offs   = (int*)  (ws + WS_OFFS);
    int*    rows   = (int*)  (ws + WS_ROWS);
    double* lpart  = (double*)(ws + WS_LPART);
    float*  nws    = (float*)(ws + WS_NSUM);

    transpose_kernel<<<1024, 256, 0, stream>>>(z_e, embed, flat, xhp, out + O_ZE,
                                               ehp, nlp, (uint4*)(ws + WS_COUNTS));
    nn_kernel<<<dim3(128, 4), 256, 0, stream>>>(xhp, ehp, nlp, p_pk);
    reduce_refine_kernel<<<M_ / 256, 256, 0, stream>>>(p_pk, flat, embed, nlp,
                                                       idxws, out + O_IDX, counts);
    gather_kernel<<<4096, 256, 0, stream>>>(embed, idxws, out + O_ZQST, out + O_ZQ);
    ema_a_kernel<<<1, 1024, 0, stream>>>(cluster_size, counts, out + O_NCS, nws, offs);
    bucket_kernel<<<M_ / 256, 256, 0, stream>>>(idxws, offs, cur, rows,
                                                (float4*)(ws + WS_ESUM));
    chunksum_kernel<<<M_ / 64, K_, 0, stream>>>(flat, embed, rows, idxws, esum, lpart);
    ema_b_kernel<<<(N_ * K_) / 256, 256, 0, stream>>>(embed_avg, esum, out + O_NCS, nws,
                                                      lpart, out + O_NEA, out + O_EMB,
                                                      out + O_LOSS);
}